// Round 1
// baseline (198.089 us; speedup 1.0000x reference)
//
#include <hip/hip_runtime.h>

namespace {
constexpr int NB  = 8;
constexpr int N1  = 4096;
constexpr int N2  = 1024;
constexpr int F1  = 128;
constexpr int F2  = 256;
constexpr int H1  = 256;
constexpr int H2  = 256;
constexpr int TM  = 64;   // rows per block
constexpr int TK  = 32;   // K-chunk
constexpr float SLOPE = 0.2f;
constexpr float EPSD  = 1e-10f;
}

__device__ __forceinline__ void fma4(float4& a, float s, const float4& b) {
  a.x = fmaf(s, b.x, a.x);
  a.y = fmaf(s, b.y, a.y);
  a.z = fmaf(s, b.z, a.z);
  a.w = fmaf(s, b.w, a.w);
}

__device__ __forceinline__ float lrelu(float x) {
  return x >= 0.0f ? x : SLOPE * x;
}

__global__ __launch_bounds__(256, 2)
void fp_fused(const float* __restrict__ xyz1, const float* __restrict__ xyz2,
              const float* __restrict__ points1, const float* __restrict__ points2,
              const float* __restrict__ W1, const float* __restrict__ b1,
              const float* __restrict__ W2, const float* __restrict__ b2,
              float* __restrict__ out)
{
  __shared__ int   s_idx[TM][3];
  __shared__ float s_w[TM][3];
  __shared__ float s_big[10496];   // phase A: 5632 used; phase B: A_t(2304)+B_t(8192)

  const int t    = threadIdx.x;
  const int b    = blockIdx.x / (N1 / TM);
  const int row0 = (blockIdx.x % (N1 / TM)) * TM;

  // ================= Phase A: 3-NN + weights =================
  {
    float* xyz2s = s_big;                 // 3072 floats
    float* sq2   = s_big + 3072;          // 1024
    float* candD = s_big + 4096;          // 768
    int*   candI = (int*)(s_big + 4864);  // 768

    for (int i = t; i < 3 * N2; i += 256) xyz2s[i] = xyz2[b * 3 * N2 + i];
    __syncthreads();
    for (int j = t; j < N2; j += 256) {
      float x = xyz2s[3*j], y = xyz2s[3*j+1], z = xyz2s[3*j+2];
      sq2[j] = x*x + y*y + z*z;
    }
    __syncthreads();

    {
      const int r = t >> 2, part = t & 3;
      const int row = row0 + r;
      const float px = xyz1[(b*N1 + row)*3 + 0];
      const float py = xyz1[(b*N1 + row)*3 + 1];
      const float pz = xyz1[(b*N1 + row)*3 + 2];
      const float sq1 = px*px + py*py + pz*pz;
      float d0 = 3.4e38f, d1 = 3.4e38f, d2 = 3.4e38f;
      int   i0 = 0, i1 = 0, i2 = 0;
      const int jb = part * 256;
      for (int j = jb; j < jb + 256; ++j) {
        float dot = px*xyz2s[3*j] + py*xyz2s[3*j+1] + pz*xyz2s[3*j+2];
        float d = sq1 + sq2[j] - 2.0f * dot;
        if (d < d2) {
          if (d < d1) {
            d2 = d1; i2 = i1;
            if (d < d0) { d1 = d0; i1 = i0; d0 = d; i0 = j; }
            else        { d1 = d;  i1 = j; }
          } else { d2 = d; i2 = j; }
        }
      }
      candD[t*3+0] = d0; candD[t*3+1] = d1; candD[t*3+2] = d2;
      candI[t*3+0] = i0; candI[t*3+1] = i1; candI[t*3+2] = i2;
    }
    __syncthreads();

    if (t < TM) {
      float d0 = 3.4e38f, d1 = 3.4e38f, d2 = 3.4e38f;
      int   i0 = 0, i1 = 0, i2 = 0;
      for (int p = 0; p < 4; ++p) {
        for (int c = 0; c < 3; ++c) {
          float d = candD[(t*4 + p)*3 + c];
          int  ii = candI[(t*4 + p)*3 + c];
          if (d < d2) {
            if (d < d1) {
              d2 = d1; i2 = i1;
              if (d < d0) { d1 = d0; i1 = i0; d0 = d; i0 = ii; }
              else        { d1 = d;  i1 = ii; }
            } else { d2 = d; i2 = ii; }
          }
        }
      }
      d0 = fmaxf(d0, EPSD); d1 = fmaxf(d1, EPSD); d2 = fmaxf(d2, EPSD);
      float w0 = 1.0f/d0, w1 = 1.0f/d1, w2 = 1.0f/d2;
      float inv = 1.0f/(w0 + w1 + w2);
      s_idx[t][0] = i0; s_idx[t][1] = i1; s_idx[t][2] = i2;
      s_w[t][0] = w0*inv; s_w[t][1] = w1*inv; s_w[t][2] = w2*inv;
    }
    __syncthreads();
  }

  // ================= Phase B: fused GEMM1 + GEMM2 =================
  float* A_t = s_big;            // 64 x 36 (padded)  = 2304
  float* B_t = s_big + 2304;     // 32 x 256          = 8192

  const int tx = t & 15;         // 16 col-groups
  const int ty = t >> 4;         // 16 row-groups (4 rows each)

  float4 acc[4][4];
  #pragma unroll
  for (int i = 0; i < 4; ++i)
    #pragma unroll
    for (int c = 0; c < 4; ++c)
      acc[i][c] = make_float4(0.f, 0.f, 0.f, 0.f);

  // staging role: 4 threads per row, 8 cols each
  const int rr = t >> 2;
  const int c8 = (t & 3) * 8;
  const float w0 = s_w[rr][0], w1 = s_w[rr][1], w2 = s_w[rr][2];
  const int   g0 = s_idx[rr][0], g1 = s_idx[rr][1], g2 = s_idx[rr][2];
  const float* p2b = points2 + (size_t)b * N2 * F2;
  const float* p1r = points1 + ((size_t)b * N1 + row0 + rr) * F1;

  // ---- GEMM1: x(64x384) @ W1(384x256) ----
  for (int kc = 0; kc < (F2 + F1) / TK; ++kc) {
    const int k0 = kc * TK;
    // stage A tile (gathered interp for k<256, points1 after)
    if (k0 < F2) {
      const float* q0 = p2b + (size_t)g0 * F2 + k0 + c8;
      const float* q1 = p2b + (size_t)g1 * F2 + k0 + c8;
      const float* q2 = p2b + (size_t)g2 * F2 + k0 + c8;
      float4 u0 = *(const float4*)q0, v0 = *(const float4*)(q0 + 4);
      float4 u1 = *(const float4*)q1, v1 = *(const float4*)(q1 + 4);
      float4 u2 = *(const float4*)q2, v2 = *(const float4*)(q2 + 4);
      float4 lo = make_float4(0.f,0.f,0.f,0.f), hi = make_float4(0.f,0.f,0.f,0.f);
      fma4(lo, w0, u0); fma4(lo, w1, u1); fma4(lo, w2, u2);
      fma4(hi, w0, v0); fma4(hi, w1, v1); fma4(hi, w2, v2);
      *(float4*)&A_t[rr*36 + c8]     = lo;
      *(float4*)&A_t[rr*36 + c8 + 4] = hi;
    } else {
      const float* q = p1r + (k0 - F2) + c8;
      *(float4*)&A_t[rr*36 + c8]     = *(const float4*)q;
      *(float4*)&A_t[rr*36 + c8 + 4] = *(const float4*)(q + 4);
    }
    // stage B tile: W1 rows k0..k0+31 (contiguous 8192 floats)
    {
      const float4* src = (const float4*)(W1 + (size_t)k0 * H1);
      float4* dst = (float4*)B_t;
      for (int i = t; i < TK * H1 / 4; i += 256) dst[i] = src[i];
    }
    __syncthreads();
    #pragma unroll 8
    for (int kk = 0; kk < TK; ++kk) {
      float a0 = A_t[(ty*4 + 0)*36 + kk];
      float a1 = A_t[(ty*4 + 1)*36 + kk];
      float a2 = A_t[(ty*4 + 2)*36 + kk];
      float a3 = A_t[(ty*4 + 3)*36 + kk];
      #pragma unroll
      for (int cb = 0; cb < 4; ++cb) {
        float4 bv = *(float4*)&B_t[kk*256 + cb*64 + tx*4];
        fma4(acc[0][cb], a0, bv);
        fma4(acc[1][cb], a1, bv);
        fma4(acc[2][cb], a2, bv);
        fma4(acc[3][cb], a3, bv);
      }
    }
    __syncthreads();
  }

  // bias + leaky -> acc becomes h (registers)
  #pragma unroll
  for (int i = 0; i < 4; ++i) {
    #pragma unroll
    for (int cb = 0; cb < 4; ++cb) {
      const int col = cb*64 + tx*4;
      float4 bb = *(const float4*)&b1[col];
      float4 v = acc[i][cb];
      v.x = lrelu(v.x + bb.x); v.y = lrelu(v.y + bb.y);
      v.z = lrelu(v.z + bb.z); v.w = lrelu(v.w + bb.w);
      acc[i][cb] = v;
    }
  }

  // ---- GEMM2: h(64x256) @ W2(256x256) ----
  float4 acc2[4][4];
  #pragma unroll
  for (int i = 0; i < 4; ++i)
    #pragma unroll
    for (int c = 0; c < 4; ++c)
      acc2[i][c] = make_float4(0.f, 0.f, 0.f, 0.f);

  for (int kc = 0; kc < H1 / TK; ++kc) {
    const int k0 = kc * TK;
    // stage A tile from the h registers: owners of cols [k0, k0+32)
    {
      const int cbSel = k0 >> 6;          // which 64-col block
      const int txLo  = (k0 & 63) >> 2;   // first tx owning this 32-col window
      if (tx >= txLo && tx < txLo + 8) {
        const int cc = (tx - txLo) * 4;
        #pragma unroll
        for (int i = 0; i < 4; ++i)
          *(float4*)&A_t[(ty*4 + i)*36 + cc] = acc[i][cbSel];
      }
    }
    // stage B tile: W2 rows k0..k0+31
    {
      const float4* src = (const float4*)(W2 + (size_t)k0 * H2);
      float4* dst = (float4*)B_t;
      for (int i = t; i < TK * H2 / 4; i += 256) dst[i] = src[i];
    }
    __syncthreads();
    #pragma unroll 8
    for (int kk = 0; kk < TK; ++kk) {
      float a0 = A_t[(ty*4 + 0)*36 + kk];
      float a1 = A_t[(ty*4 + 1)*36 + kk];
      float a2 = A_t[(ty*4 + 2)*36 + kk];
      float a3 = A_t[(ty*4 + 3)*36 + kk];
      #pragma unroll
      for (int cb = 0; cb < 4; ++cb) {
        float4 bv = *(float4*)&B_t[kk*256 + cb*64 + tx*4];
        fma4(acc2[0][cb], a0, bv);
        fma4(acc2[1][cb], a1, bv);
        fma4(acc2[2][cb], a2, bv);
        fma4(acc2[3][cb], a3, bv);
      }
    }
    __syncthreads();
  }

  // epilogue: bias + leaky -> out
  float* outp = out + ((size_t)b * N1 + row0) * H2;
  #pragma unroll
  for (int i = 0; i < 4; ++i) {
    const int row = ty*4 + i;
    #pragma unroll
    for (int cb = 0; cb < 4; ++cb) {
      const int col = cb*64 + tx*4;
      float4 bb = *(const float4*)&b2[col];
      float4 v = acc2[i][cb];
      v.x = lrelu(v.x + bb.x); v.y = lrelu(v.y + bb.y);
      v.z = lrelu(v.z + bb.z); v.w = lrelu(v.w + bb.w);
      *(float4*)&outp[(size_t)row * H2 + col] = v;
    }
  }
}

extern "C" void kernel_launch(void* const* d_in, const int* in_sizes, int n_in,
                              void* d_out, int out_size, void* d_ws, size_t ws_size,
                              hipStream_t stream) {
  const float* xyz1    = (const float*)d_in[0];
  const float* xyz2    = (const float*)d_in[1];
  const float* points1 = (const float*)d_in[2];
  const float* points2 = (const float*)d_in[3];
  const float* W1      = (const float*)d_in[4];
  const float* b1      = (const float*)d_in[5];
  const float* W2      = (const float*)d_in[6];
  const float* b2      = (const float*)d_in[7];
  float* out = (float*)d_out;

  dim3 grid(NB * (N1 / TM));
  dim3 block(256);
  hipLaunchKernelGGL(fp_fused, grid, block, 0, stream,
                     xyz1, xyz2, points1, points2, W1, b1, W2, b2, out);
}

// Round 2
// 64.881 us; speedup vs baseline: 3.0531x; 3.0531x over previous
//
#include <hip/hip_runtime.h>

typedef __attribute__((ext_vector_type(8))) short bf16x8;
typedef __attribute__((ext_vector_type(4))) float f32x4;
typedef const __attribute__((address_space(1))) void GV;
typedef __attribute__((address_space(3))) void LV;

namespace {
constexpr int NB = 8, N1 = 4096, N2 = 1024, F1 = 128, F2 = 256, H1 = 256, H2 = 256;
constexpr int TM = 64;
constexpr float SLOPE = 0.2f;
constexpr float EPSD  = 1e-10f;
constexpr int WS1_BYTES = 6 * 32768;   // W1: 6 chunks of [256n][64k] bf16, swizzled
constexpr int WS2_BYTES = 8 * 16384;   // W2: 8 chunks of [256n][32k] bf16, swizzled
}

__device__ __forceinline__ unsigned short f2bf(float f) {
  union { float f; unsigned u; } v; v.f = f;
  unsigned r = v.u + 0x7FFFu + ((v.u >> 16) & 1u);   // RNE
  return (unsigned short)(r >> 16);
}
__device__ __forceinline__ float lrelu(float x) { return x >= 0.f ? x : SLOPE * x; }

__device__ __forceinline__ void glds16(const void* g, void* l) {
  __builtin_amdgcn_global_load_lds((GV*)g, (LV*)l, 16, 0, 0);
}

// ---- W pre-transform: f32 [k][n] -> bf16 transposed [n][k], chunked + bank-swizzled ----
__global__ __launch_bounds__(256)
void transform_w(const float* __restrict__ W1, const float* __restrict__ W2,
                 char* __restrict__ ws)
{
  int id = blockIdx.x * 256 + threadIdx.x;
  if (id < 6 * 256 * 8) {                       // W1: chunk c, col n, k-group g (8 bf16)
    int c = id >> 11, rem = id & 2047, n = rem >> 3, g = rem & 7;
    const float* src = W1 + (size_t)(c * 64 + g * 8) * 256 + n;
    unsigned u[4];
    #pragma unroll
    for (int p = 0; p < 4; ++p) {
      unsigned short lo = f2bf(src[(2 * p) * 256]);
      unsigned short hi = f2bf(src[(2 * p + 1) * 256]);
      u[p] = (unsigned)lo | ((unsigned)hi << 16);
    }
    *(uint4*)(ws + c * 32768 + n * 128 + ((g ^ (n & 7)) << 4)) =
        make_uint4(u[0], u[1], u[2], u[3]);
  } else if ((id -= 6 * 256 * 8) < 8 * 256 * 4) {  // W2: chunk c, col n, k-group g
    int c = id >> 10, rem = id & 1023, n = rem >> 2, g = rem & 3;
    const float* src = W2 + (size_t)(c * 32 + g * 8) * 256 + n;
    unsigned u[4];
    #pragma unroll
    for (int p = 0; p < 4; ++p) {
      unsigned short lo = f2bf(src[(2 * p) * 256]);
      unsigned short hi = f2bf(src[(2 * p + 1) * 256]);
      u[p] = (unsigned)lo | ((unsigned)hi << 16);
    }
    *(uint4*)(ws + WS1_BYTES + c * 16384 + n * 64 + ((g ^ ((n >> 1) & 3)) << 4)) =
        make_uint4(u[0], u[1], u[2], u[3]);
  }
}

// ---- fused: 3-NN interp (fp32) + MLP1 + MLP2 via bf16 MFMA ----
__global__ __launch_bounds__(256, 2)
void fp_mfma(const float* __restrict__ xyz1, const float* __restrict__ xyz2,
             const float* __restrict__ p1,   const float* __restrict__ p2,
             const char* __restrict__ ws,
             const float* __restrict__ b1,   const float* __restrict__ b2,
             float* __restrict__ out)
{
  __shared__ __align__(16) char smem[49152];
  __shared__ int   s_idx[TM][3];
  __shared__ float s_w[TM][3];

  const int t    = threadIdx.x;
  const int b    = blockIdx.x & 7;          // XCD-aware: batch == XCD -> L2-resident points2
  const int row0 = (blockIdx.x >> 3) * TM;

  // ================= Phase A: 3-NN + inverse-distance weights (fp32) =================
  {
    float4* xyz2q = (float4*)smem;                  // [0, 16384)
    float*  candD = (float*)(smem + 16384);         // 768 floats
    int*    candI = (int*)  (smem + 19456);         // 768 ints
    const float* xz2 = xyz2 + (size_t)b * N2 * 3;
    for (int j = t; j < N2; j += 256) {
      float x = xz2[3 * j], y = xz2[3 * j + 1], z = xz2[3 * j + 2];
      xyz2q[j] = make_float4(x, y, z, x * x + y * y + z * z);
    }
    __syncthreads();
    {
      const int r = t >> 2, part = t & 3;
      const float* x1 = xyz1 + ((size_t)b * N1 + row0 + r) * 3;
      const float px = x1[0], py = x1[1], pz = x1[2];
      const float sq1 = px * px + py * py + pz * pz;
      float d0 = 3.4e38f, d1 = 3.4e38f, d2 = 3.4e38f;
      int   i0 = 0, i1 = 0, i2 = 0;
      #pragma unroll 4
      for (int j = part * 256; j < part * 256 + 256; ++j) {
        float4 q = xyz2q[j];
        float dot = px * q.x + py * q.y + pz * q.z;
        float d = fmaf(-2.f, dot, sq1 + q.w);
        if (d < d2) {
          if (d < d1) {
            d2 = d1; i2 = i1;
            if (d < d0) { d1 = d0; i1 = i0; d0 = d; i0 = j; }
            else        { d1 = d;  i1 = j; }
          } else { d2 = d; i2 = j; }
        }
      }
      candD[t * 3 + 0] = d0; candD[t * 3 + 1] = d1; candD[t * 3 + 2] = d2;
      candI[t * 3 + 0] = i0; candI[t * 3 + 1] = i1; candI[t * 3 + 2] = i2;
    }
    __syncthreads();
    if (t < TM) {
      float d0 = 3.4e38f, d1 = 3.4e38f, d2 = 3.4e38f;
      int   i0 = 0, i1 = 0, i2 = 0;
      for (int p = 0; p < 4; ++p)
        for (int c = 0; c < 3; ++c) {
          float d = candD[(t * 4 + p) * 3 + c];
          int  ii = candI[(t * 4 + p) * 3 + c];
          if (d < d2) {
            if (d < d1) {
              d2 = d1; i2 = i1;
              if (d < d0) { d1 = d0; i1 = i0; d0 = d; i0 = ii; }
              else        { d1 = d;  i1 = ii; }
            } else { d2 = d; i2 = ii; }
          }
        }
      d0 = fmaxf(d0, EPSD); d1 = fmaxf(d1, EPSD); d2 = fmaxf(d2, EPSD);
      float w0 = 1.f / d0, w1 = 1.f / d1, w2 = 1.f / d2;
      float inv = 1.f / (w0 + w1 + w2);
      s_idx[t][0] = i0; s_idx[t][1] = i1; s_idx[t][2] = i2;
      s_w[t][0] = w0 * inv; s_w[t][1] = w1 * inv; s_w[t][2] = w2 * inv;
    }
    __syncthreads();
  }

  // ================= Phase B: MFMA GEMMs =================
  const int lane = t & 63, w = t >> 6;
  const int lrow = lane & 15, lg = lane >> 4;   // MFMA row/col index, k-group
  char* At  = smem;               // [0, 8192)        64 x 64 bf16, swizzled
  char* Bt  = smem + 8192;        // [8192, 40960)    256n x 64k bf16, swizzled
  char* B2t = smem + 32768;       // [32768, 49152)   256n x 32k bf16, swizzled (GEMM2)

  f32x4 acc[4][4];
  #pragma unroll
  for (int mt = 0; mt < 4; ++mt)
    #pragma unroll
    for (int nt = 0; nt < 4; ++nt)
      acc[mt][nt] = (f32x4){0.f, 0.f, 0.f, 0.f};

  const int rr = t >> 2, qq = t & 3;            // staging: 4 threads/row, 16 k each
  const float w0 = s_w[rr][0], w1_ = s_w[rr][1], w2_ = s_w[rr][2];
  const int   g0 = s_idx[rr][0], g1 = s_idx[rr][1], g2 = s_idx[rr][2];
  const float* p2b = p2 + (size_t)b * N2 * F2;
  const float* p1r = p1 + ((size_t)b * N1 + row0 + rr) * F1;
  const char* ws1 = ws;
  const char* ws2 = ws + WS1_BYTES;

  // ---- GEMM1: x(64x384) @ W1 -> acc ----
  for (int kc = 0; kc < 6; ++kc) {
    {  // stage A: interp (fp32) -> bf16, swizzled ds_write_b128
      float v[16];
      const int k0 = kc * 64 + qq * 16;
      if (kc < 4) {
        const float4* q0 = (const float4*)(p2b + (size_t)g0 * F2 + k0);
        const float4* q1 = (const float4*)(p2b + (size_t)g1 * F2 + k0);
        const float4* q2 = (const float4*)(p2b + (size_t)g2 * F2 + k0);
        #pragma unroll
        for (int p = 0; p < 4; ++p) {
          float4 a0 = q0[p], a1 = q1[p], a2 = q2[p];
          v[4*p+0] = fmaf(w2_, a2.x, fmaf(w1_, a1.x, w0 * a0.x));
          v[4*p+1] = fmaf(w2_, a2.y, fmaf(w1_, a1.y, w0 * a0.y));
          v[4*p+2] = fmaf(w2_, a2.z, fmaf(w1_, a1.z, w0 * a0.z));
          v[4*p+3] = fmaf(w2_, a2.w, fmaf(w1_, a1.w, w0 * a0.w));
        }
      } else {
        const float4* q = (const float4*)(p1r + (k0 - F2));
        #pragma unroll
        for (int p = 0; p < 4; ++p) {
          float4 a = q[p];
          v[4*p+0] = a.x; v[4*p+1] = a.y; v[4*p+2] = a.z; v[4*p+3] = a.w;
        }
      }
      unsigned u[8];
      #pragma unroll
      for (int p = 0; p < 8; ++p)
        u[p] = (unsigned)f2bf(v[2*p]) | ((unsigned)f2bf(v[2*p+1]) << 16);
      const int r7 = rr & 7;
      *(uint4*)(At + rr * 128 + (((qq*2    ) ^ r7) << 4)) = make_uint4(u[0], u[1], u[2], u[3]);
      *(uint4*)(At + rr * 128 + (((qq*2 + 1) ^ r7) << 4)) = make_uint4(u[4], u[5], u[6], u[7]);
    }
    {  // stage B: 32KB via global_load_lds x8 (pre-swizzled source, linear dest)
      const char* src = ws1 + kc * 32768 + t * 16;
      char* dst = Bt + t * 16;
      #pragma unroll
      for (int r = 0; r < 8; ++r) glds16(src + r * 4096, dst + r * 4096);
    }
    __syncthreads();
    #pragma unroll
    for (int ks = 0; ks < 2; ++ks) {
      const int gg = ks * 4 + lg;
      const int sw = (gg ^ (lrow & 7)) << 4;
      bf16x8 af[4], bfr[4];
      #pragma unroll
      for (int mt = 0; mt < 4; ++mt)
        af[mt] = *(const bf16x8*)(At + (mt * 16 + lrow) * 128 + sw);
      #pragma unroll
      for (int nt = 0; nt < 4; ++nt)
        bfr[nt] = *(const bf16x8*)(Bt + (w * 64 + nt * 16 + lrow) * 128 + sw);
      #pragma unroll
      for (int mt = 0; mt < 4; ++mt)
        #pragma unroll
        for (int nt = 0; nt < 4; ++nt)
          acc[mt][nt] = __builtin_amdgcn_mfma_f32_16x16x32_bf16(af[mt], bfr[nt], acc[mt][nt], 0, 0, 0);
    }
    __syncthreads();
  }

  // ---- h = lrelu(acc + b1) -> LDS [64 rows][256 k] bf16, swizzled (row stride 512B) ----
  {
    float bb[4];
    #pragma unroll
    for (int nt = 0; nt < 4; ++nt) bb[nt] = b1[w * 64 + nt * 16 + lrow];
    #pragma unroll
    for (int mt = 0; mt < 4; ++mt)
      #pragma unroll
      for (int rg = 0; rg < 4; ++rg) {
        const int row = mt * 16 + lg * 4 + rg;
        const int rb = row * 512, r7 = row & 7;
        #pragma unroll
        for (int nt = 0; nt < 4; ++nt) {
          const int col = w * 64 + nt * 16 + lrow;
          unsigned short hv = f2bf(lrelu(acc[mt][nt][rg] + bb[nt]));
          *(short*)(smem + rb + (((col >> 3) ^ r7) << 4) + ((lrow & 7) * 2)) = (short)hv;
        }
      }
  }
  __syncthreads();

  // ---- GEMM2: h(64x256) @ W2 -> acc2 ----
  f32x4 acc2[4][4];
  #pragma unroll
  for (int mt = 0; mt < 4; ++mt)
    #pragma unroll
    for (int nt = 0; nt < 4; ++nt)
      acc2[mt][nt] = (f32x4){0.f, 0.f, 0.f, 0.f};

  for (int kc = 0; kc < 8; ++kc) {
    {  // stage B2: 16KB via global_load_lds x4
      const char* src = ws2 + kc * 16384 + t * 16;
      char* dst = B2t + t * 16;
      #pragma unroll
      for (int r = 0; r < 4; ++r) glds16(src + r * 4096, dst + r * 4096);
    }
    __syncthreads();
    const int gg = kc * 4 + lg;                       // 0..31, XOR affects low 3 bits
    const int swA = (gg ^ (lrow & 7)) << 4;
    bf16x8 af[4], bfr[4];
    #pragma unroll
    for (int mt = 0; mt < 4; ++mt)
      af[mt] = *(const bf16x8*)(smem + (mt * 16 + lrow) * 512 + swA);
    #pragma unroll
    for (int nt = 0; nt < 4; ++nt) {
      const int n = w * 64 + nt * 16 + lrow;
      bfr[nt] = *(const bf16x8*)(B2t + n * 64 + ((lg ^ ((n >> 1) & 3)) << 4));
    }
    #pragma unroll
    for (int mt = 0; mt < 4; ++mt)
      #pragma unroll
      for (int nt = 0; nt < 4; ++nt)
        acc2[mt][nt] = __builtin_amdgcn_mfma_f32_16x16x32_bf16(af[mt], bfr[nt], acc2[mt][nt], 0, 0, 0);
    __syncthreads();
  }

  // ---- epilogue: out = lrelu(acc2 + b2) ----
  {
    float bb[4];
    #pragma unroll
    for (int nt = 0; nt < 4; ++nt) bb[nt] = b2[w * 64 + nt * 16 + lrow];
    float* ob = out + ((size_t)b * N1 + row0) * H2;
    #pragma unroll
    for (int mt = 0; mt < 4; ++mt)
      #pragma unroll
      for (int rg = 0; rg < 4; ++rg) {
        const int row = mt * 16 + lg * 4 + rg;
        #pragma unroll
        for (int nt = 0; nt < 4; ++nt) {
          const int col = w * 64 + nt * 16 + lrow;
          ob[(size_t)row * H2 + col] = lrelu(acc2[mt][nt][rg] + bb[nt]);
        }
      }
  }
}

extern "C" void kernel_launch(void* const* d_in, const int* in_sizes, int n_in,
                              void* d_out, int out_size, void* d_ws, size_t ws_size,
                              hipStream_t stream) {
  const float* xyz1    = (const float*)d_in[0];
  const float* xyz2    = (const float*)d_in[1];
  const float* points1 = (const float*)d_in[2];
  const float* points2 = (const float*)d_in[3];
  const float* W1      = (const float*)d_in[4];
  const float* b1      = (const float*)d_in[5];
  const float* W2      = (const float*)d_in[6];
  const float* b2      = (const float*)d_in[7];
  float* out = (float*)d_out;

  hipLaunchKernelGGL(transform_w, dim3(80), dim3(256), 0, stream, W1, W2, (char*)d_ws);
  hipLaunchKernelGGL(fp_mfma, dim3(NB * (N1 / TM)), dim3(256), 0, stream,
                     xyz1, xyz2, points1, points2, (const char*)d_ws, b1, b2, out);
}

// Round 3
// 60.535 us; speedup vs baseline: 3.2723x; 1.0718x over previous
//
#include <hip/hip_runtime.h>

typedef __attribute__((ext_vector_type(8))) short bf16x8;
typedef __attribute__((ext_vector_type(4))) float f32x4;
typedef const __attribute__((address_space(1))) void GV;
typedef __attribute__((address_space(3))) void LV;

namespace {
constexpr int NB=8, N1=4096, N2=1024, F1=128, F2=256, H1=256, H2=256;
constexpr int TM=64;
constexpr float SLOPE=0.2f, EPSD=1e-10f;
constexpr int WS_XYZ = 0;                  // 8*1024*16 = 131072 B
constexpr int WS_W1  = 131072;             // 12 chunks * 16384 = 196608 B
constexpr int WS_W2  = 327680;             // 8 chunks * 16384 = 131072 B (total 458752)
}

__device__ __forceinline__ unsigned short f2bf(float f){
  union{float f; unsigned u;} v; v.f=f;
  unsigned r = v.u + 0x7FFFu + ((v.u>>16)&1u);   // RNE
  return (unsigned short)(r>>16);
}
__device__ __forceinline__ float lrelu(float x){ return x>=0.f? x : SLOPE*x; }
__device__ __forceinline__ void glds16(const void* g, void* l){
  __builtin_amdgcn_global_load_lds((GV*)g,(LV*)l,16,0,0);
}

// ---- pre-transform: W1/W2 -> bf16 transposed chunked [n][k] with bank-swizzled
// slots (slot = n*4 + (g ^ ((n>>1)&3)) within each 32k-chunk); xyz2 -> (x,y,z,sq).
__global__ __launch_bounds__(256)
void transform_w(const float* __restrict__ W1, const float* __restrict__ W2,
                 const float* __restrict__ xyz2, char* __restrict__ ws)
{
  int id = blockIdx.x * 256 + threadIdx.x;
  if (id < 12288) {                      // W1T: 12 chunks x 256 n x 4 groups
    int c = id >> 10, rem = id & 1023, n = rem >> 2, g = rem & 3;
    const float* src = W1 + (size_t)(32*c + 8*g) * 256 + n;
    unsigned u[4];
    #pragma unroll
    for (int p = 0; p < 4; ++p) {
      unsigned short lo = f2bf(src[(2*p)*256]);
      unsigned short hi = f2bf(src[(2*p+1)*256]);
      u[p] = (unsigned)lo | ((unsigned)hi << 16);
    }
    *(uint4*)(ws + WS_W1 + c*16384 + (n*4 + (g ^ ((n>>1)&3)))*16) =
        make_uint4(u[0],u[1],u[2],u[3]);
  } else if (id < 20480) {               // W2T: 8 chunks
    id -= 12288;
    int c = id >> 10, rem = id & 1023, n = rem >> 2, g = rem & 3;
    const float* src = W2 + (size_t)(32*c + 8*g) * 256 + n;
    unsigned u[4];
    #pragma unroll
    for (int p = 0; p < 4; ++p) {
      unsigned short lo = f2bf(src[(2*p)*256]);
      unsigned short hi = f2bf(src[(2*p+1)*256]);
      u[p] = (unsigned)lo | ((unsigned)hi << 16);
    }
    *(uint4*)(ws + WS_W2 + c*16384 + (n*4 + (g ^ ((n>>1)&3)))*16) =
        make_uint4(u[0],u[1],u[2],u[3]);
  } else if (id < 28672) {               // xyz2q: (x,y,z,sq)
    id -= 20480;
    int bb = id >> 10, j = id & 1023;
    const float* s = xyz2 + ((size_t)bb*N2 + j)*3;
    float x = s[0], y = s[1], z = s[2];
    *(float4*)(ws + WS_XYZ + ((size_t)bb*1024 + j)*16) =
        make_float4(x, y, z, x*x + y*y + z*z);
  }
}

// ---- fused: 3-NN (scalar-uniform scan) + MLP1 + MLP2 (bf16 MFMA, dbuf W stages)
__global__ __launch_bounds__(256, 2)
void fp_mfma(const float* __restrict__ xyz1, const float* __restrict__ p1,
             const float* __restrict__ p2,   const char* __restrict__ ws,
             const float* __restrict__ b1,   const float* __restrict__ b2,
             float* __restrict__ out)
{
  __shared__ __align__(16) char smem[65536];
  char* Xt  = smem;            // [0,24576): x half-tile [64m][24 slots]; later h [0,32768)
  char* Wb0 = smem + 32768;    // 16KB chunk buffer 0
  char* Wb1 = smem + 49152;    // 16KB chunk buffer 1

  const int t = threadIdx.x;
  const int b = blockIdx.x & 7;            // batch == XCD -> L2-resident inputs
  const int row0 = (blockIdx.x >> 3) * TM;
  const int lane = t & 63, wv = t >> 6;
  const int lrow = lane & 15, lg = lane >> 4;

  // ================= Phase A: 3-NN, lane=row, wave=j-slice, uniform loads ======
  {
    const float4* x2q = (const float4*)(ws + WS_XYZ + (size_t)b*16384);
    const float* x1 = xyz1 + ((size_t)b*N1 + row0 + lane)*3;
    const float px = x1[0], py = x1[1], pz = x1[2];
    const float sq1 = px*px + py*py + pz*pz;
    float d0=3.4e38f, d1=3.4e38f, d2=3.4e38f;
    int i0=0, i1=0, i2=0;
    const int j0 = wv*256;
    #pragma unroll 4
    for (int j = j0; j < j0+256; ++j) {
      float4 q = x2q[j];                               // wave-uniform -> s_load
      float dot = px*q.x + py*q.y + pz*q.z;
      float d = fmaf(-2.f, dot, sq1 + q.w);
      bool c0 = d < d0, c1 = d < d1, c2 = d < d2;
      i2 = c1 ? i1 : (c2 ? j : i2);
      i1 = c0 ? i0 : (c1 ? j : i1);
      i0 = c0 ? j  : i0;
      d2 = __builtin_amdgcn_fmed3f(d, d1, d2);
      d1 = __builtin_amdgcn_fmed3f(d, d0, d1);
      d0 = fminf(d, d0);
    }
    float* cd = (float*)Xt + (wv*64 + lane)*8;
    cd[0]=d0; cd[1]=d1; cd[2]=d2;
    ((int*)cd)[4]=i0; ((int*)cd)[5]=i1; ((int*)cd)[6]=i2;
  }
  __syncthreads();
  if (t < 64) {                                        // merge 4 wave-candidates
    float d0=3.4e38f,d1=3.4e38f,d2=3.4e38f; int i0=0,i1=0,i2=0;
    for (int p=0;p<4;++p){
      const float* cd = (const float*)Xt + (p*64 + t)*8;
      for (int c=0;c<3;++c){
        float d = cd[c]; int ii = ((const int*)cd)[4+c];
        if (d < d2) {
          if (d < d1) { d2=d1; i2=i1;
            if (d < d0) { d1=d0; i1=i0; d0=d; i0=ii; } else { d1=d; i1=ii; }
          } else { d2=d; i2=ii; }
        }
      }
    }
    d0=fmaxf(d0,EPSD); d1=fmaxf(d1,EPSD); d2=fmaxf(d2,EPSD);
    float w0=1.f/d0, w1=1.f/d1, w2=1.f/d2, inv=1.f/(w0+w1+w2);
    float* sw = (float*)Wb0 + t*8;
    sw[0]=w0*inv; sw[1]=w1*inv; sw[2]=w2*inv;
    ((int*)sw)[4]=i0; ((int*)sw)[5]=i1; ((int*)sw)[6]=i2;
  }
  __syncthreads();
  const int rr = t >> 2, qq = t & 3;
  float w0_, w1_, w2_; int g0, g1, g2;
  {
    const float* sw = (const float*)Wb0 + rr*8;
    w0_=sw[0]; w1_=sw[1]; w2_=sw[2];
    g0=((const int*)sw)[4]; g1=((const int*)sw)[5]; g2=((const int*)sw)[6];
  }
  __syncthreads();

  // ================= Phase B =================
  const char* wsW1 = ws + WS_W1;
  const char* wsW2 = ws + WS_W2;
  const float* p2b = p2 + (size_t)b*N2*F2;
  const float* p1r = p1 + ((size_t)b*N1 + row0 + rr)*F1;
  const int r7 = rr & 7;

  // Xt half-tile builder: global kc index (0..5), local slot base kcl*8
  auto buildXt = [&](int kcg, int kcl) {
    float v[16];
    const int k0 = kcg*64 + qq*16;
    if (kcg < 4) {
      const float4* q0 = (const float4*)(p2b + (size_t)g0*F2 + k0);
      const float4* q1 = (const float4*)(p2b + (size_t)g1*F2 + k0);
      const float4* q2 = (const float4*)(p2b + (size_t)g2*F2 + k0);
      #pragma unroll
      for (int p = 0; p < 4; ++p) {
        float4 a0 = q0[p], a1 = q1[p], a2 = q2[p];
        v[4*p+0] = fmaf(w2_, a2.x, fmaf(w1_, a1.x, w0_*a0.x));
        v[4*p+1] = fmaf(w2_, a2.y, fmaf(w1_, a1.y, w0_*a0.y));
        v[4*p+2] = fmaf(w2_, a2.z, fmaf(w1_, a1.z, w0_*a0.z));
        v[4*p+3] = fmaf(w2_, a2.w, fmaf(w1_, a1.w, w0_*a0.w));
      }
    } else {
      const float4* q = (const float4*)(p1r + (k0 - F2));
      #pragma unroll
      for (int p = 0; p < 4; ++p) {
        float4 a = q[p];
        v[4*p+0]=a.x; v[4*p+1]=a.y; v[4*p+2]=a.z; v[4*p+3]=a.w;
      }
    }
    unsigned u[8];
    #pragma unroll
    for (int p = 0; p < 8; ++p)
      u[p] = (unsigned)f2bf(v[2*p]) | ((unsigned)f2bf(v[2*p+1]) << 16);
    *(uint4*)(Xt + rr*384 + (((kcl*8 + qq*2    ) ^ r7) << 4)) = make_uint4(u[0],u[1],u[2],u[3]);
    *(uint4*)(Xt + rr*384 + (((kcl*8 + qq*2 + 1) ^ r7) << 4)) = make_uint4(u[4],u[5],u[6],u[7]);
  };
  auto stage = [&](const char* src, char* dst) {
    #pragma unroll
    for (int r = 0; r < 4; ++r) glds16(src + t*16 + r*4096, dst + t*16 + r*4096);
  };

  f32x4 acc[4][4];
  #pragma unroll
  for (int mt=0;mt<4;++mt)
    #pragma unroll
    for (int nt=0;nt<4;++nt) acc[mt][nt] = (f32x4){0.f,0.f,0.f,0.f};

  // ---- GEMM1: x(64x384) @ W1, 12 chunks of K=32, dbuf W, Xt in 2 halves ----
  stage(wsW1, Wb0);                         // chunk 0
  buildXt(0,0); buildXt(1,1); buildXt(2,2); // half A (k 0..191)
  __syncthreads();
  #pragma unroll
  for (int s = 0; s < 12; ++s) {
    char* Wcur = (s & 1) ? Wb1 : Wb0;
    char* Wnxt = (s & 1) ? Wb0 : Wb1;
    if (s < 11) stage(wsW1 + (s+1)*16384, Wnxt);
    const int sl = (s >= 6) ? (s - 6) : s;
    bf16x8 af[4], bw[4];
    #pragma unroll
    for (int mt=0;mt<4;++mt) {
      const int m = mt*16 + lrow;
      af[mt] = *(const bf16x8*)(Xt + m*384 + (((sl*4 + lg) ^ (m&7))<<4));
    }
    #pragma unroll
    for (int nt=0;nt<4;++nt) {
      const int n = wv*64 + nt*16 + lrow;
      bw[nt] = *(const bf16x8*)(Wcur + (n*4 + (lg ^ ((n>>1)&3)))*16);
    }
    #pragma unroll
    for (int mt=0;mt<4;++mt)
      #pragma unroll
      for (int nt=0;nt<4;++nt)
        acc[mt][nt] = __builtin_amdgcn_mfma_f32_16x16x32_bf16(af[mt], bw[nt], acc[mt][nt], 0,0,0);
    __syncthreads();
    if (s == 5) {                           // rebuild Xt with half B (k 192..383)
      buildXt(3,0); buildXt(4,1); buildXt(5,2);
      __syncthreads();
    }
  }

  // ---- h = lrelu(acc+b1) -> LDS [64m][256k] bf16 swizzled (row stride 512B) ----
  stage(wsW2, Wb0);                         // W2 chunk 0 (issue before h conversion)
  {
    float bb[4];
    #pragma unroll
    for (int nt=0;nt<4;++nt) bb[nt] = b1[wv*64 + nt*16 + lrow];
    #pragma unroll
    for (int mt=0;mt<4;++mt)
      #pragma unroll
      for (int rg=0;rg<4;++rg) {
        const int row = mt*16 + lg*4 + rg;
        const int rb = row*512, rw7 = row & 7;
        #pragma unroll
        for (int nt=0;nt<4;++nt) {
          const int col = wv*64 + nt*16 + lrow;
          unsigned short hv = f2bf(lrelu(acc[mt][nt][rg] + bb[nt]));
          *(short*)(smem + rb + (((col>>3) ^ rw7)<<4) + ((lrow&7)*2)) = (short)hv;
        }
      }
  }
  __syncthreads();

  // ---- GEMM2: h(64x256) @ W2, 8 chunks of K=32, dbuf ----
  f32x4 acc2[4][4];
  #pragma unroll
  for (int mt=0;mt<4;++mt)
    #pragma unroll
    for (int nt=0;nt<4;++nt) acc2[mt][nt] = (f32x4){0.f,0.f,0.f,0.f};
  #pragma unroll
  for (int s = 0; s < 8; ++s) {
    char* Wcur = (s & 1) ? Wb1 : Wb0;
    char* Wnxt = (s & 1) ? Wb0 : Wb1;
    if (s < 7) stage(wsW2 + (s+1)*16384, Wnxt);
    bf16x8 af[4], bw[4];
    const int swA = ((s*4 + lg) ^ (lrow & 7)) << 4;
    #pragma unroll
    for (int mt=0;mt<4;++mt)
      af[mt] = *(const bf16x8*)(smem + (mt*16 + lrow)*512 + swA);
    #pragma unroll
    for (int nt=0;nt<4;++nt) {
      const int n = wv*64 + nt*16 + lrow;
      bw[nt] = *(const bf16x8*)(Wcur + (n*4 + (lg ^ ((n>>1)&3)))*16);
    }
    #pragma unroll
    for (int mt=0;mt<4;++mt)
      #pragma unroll
      for (int nt=0;nt<4;++nt)
        acc2[mt][nt] = __builtin_amdgcn_mfma_f32_16x16x32_bf16(af[mt], bw[nt], acc2[mt][nt], 0,0,0);
    __syncthreads();
  }

  // ---- epilogue ----
  {
    float bb[4];
    #pragma unroll
    for (int nt=0;nt<4;++nt) bb[nt] = b2[wv*64 + nt*16 + lrow];
    float* ob = out + ((size_t)b*N1 + row0) * H2;
    #pragma unroll
    for (int mt=0;mt<4;++mt)
      #pragma unroll
      for (int rg=0;rg<4;++rg) {
        const int row = mt*16 + lg*4 + rg;
        #pragma unroll
        for (int nt=0;nt<4;++nt) {
          const int col = wv*64 + nt*16 + lrow;
          ob[(size_t)row*H2 + col] = lrelu(acc2[mt][nt][rg] + bb[nt]);
        }
      }
  }
}

extern "C" void kernel_launch(void* const* d_in, const int* in_sizes, int n_in,
                              void* d_out, int out_size, void* d_ws, size_t ws_size,
                              hipStream_t stream) {
  const float* xyz1    = (const float*)d_in[0];
  const float* xyz2    = (const float*)d_in[1];
  const float* points1 = (const float*)d_in[2];
  const float* points2 = (const float*)d_in[3];
  const float* W1      = (const float*)d_in[4];
  const float* b1      = (const float*)d_in[5];
  const float* W2      = (const float*)d_in[6];
  const float* b2      = (const float*)d_in[7];
  float* out = (float*)d_out;

  hipLaunchKernelGGL(transform_w, dim3(112), dim3(256), 0, stream,
                     W1, W2, xyz2, (char*)d_ws);
  hipLaunchKernelGGL(fp_mfma, dim3(NB * (N1 / TM)), dim3(256), 0, stream,
                     xyz1, points1, points2, (const char*)d_ws, b1, b2, out);
}